// Round 5
// baseline (591.209 us; speedup 1.0000x reference)
//
#include <hip/hip_runtime.h>
#include <hip/hip_bf16.h>
#include <math.h>

typedef __attribute__((ext_vector_type(8))) short bf16x8;
typedef __attribute__((ext_vector_type(4))) float f32x4;

constexpr int PCAPS = 15488;                       // 32 maps * 484
constexpr size_t NPCH = (size_t)16*256*484;        // floats per pc partial

// ---- workspace layout (bytes) ----
constexpr size_t OFF_XC_B = 0;                                   // xc bf16 [16][52][2][28][256]
constexpr size_t XC_BYTES = (size_t)16*52*2*28*256*2;
constexpr size_t OFF_WA_B = OFF_XC_B + XC_BYTES;                 // wA bf16 [256][81][256]
constexpr size_t WA_BYTES = (size_t)256*20736*2;
constexpr size_t OFF_PC_B = OFF_WA_B + WA_BYTES;                 // pc f32 [4][16][256][484]
constexpr size_t PC_BYTES = (size_t)4*NPCH*4;
constexpr size_t OFF_U_B  = OFF_PC_B + PC_BYTES;                 // u f32 [16][15488][8]
constexpr size_t U_BYTES  = (size_t)16*PCAPS*8*4;
constexpr size_t OFF_SM_B = OFF_U_B + U_BYTES;                   // small region (floats)
// small region offsets (floats)
constexpr int S_UACC = 0;      // 128
constexpr int S_Z1   = 128;    // 160
constexpr int S_TU1  = 288;    // 1280
constexpr int S_Z2   = 1568;   // 160
constexpr int S_TU2  = 1728;   // 1280  -> zero region = 3008 floats
constexpr int S_WVS  = 3008;   // 1280
constexpr int S_M    = 4288;   // 2560
constexpr int S_H1   = 6848;   // 8192
constexpr int S_H2   = 15040;  // 16384
constexpr int S_W1T  = 31424;  // 20736

__device__ __forceinline__ void glds16(const void* g, void* l) {
    __builtin_amdgcn_global_load_lds(
        (const __attribute__((address_space(1))) unsigned int*)g,
        (__attribute__((address_space(3))) unsigned int*)l, 16, 0, 0);
}

// ---------------- weight prepack: pw[oc][ic*81+khw] -> wA[oc][khw][ic] bf16; + conv1 wT
__global__ __launch_bounds__(256) void wprep_kernel(const float* __restrict__ pw,
                                                    const float* __restrict__ c1w,
                                                    __hip_bfloat16* __restrict__ wA,
                                                    float* __restrict__ w1T)
{
    const int t = threadIdx.x;
    if (blockIdx.x < 256) {
        const int oc = blockIdx.x;                 // t = ic
        const float* src = pw + (size_t)oc*20736;
        __hip_bfloat16* dst = wA + (size_t)oc*20736;
        for (int khw = 0; khw < 81; ++khw)
            dst[khw*256 + t] = __float2bfloat16(src[t*81 + khw]);
    } else {
        for (int j = 0; j < 81; ++j) w1T[j*256 + t] = c1w[t*81 + j];
    }
}

// ---------------- conv1 + relu, channel-last bf16 parity-split output
// xc[b][h][p][wc][ic], p = w&1, wc = w>>1  (wc 26,27 zeroed here)
__global__ __launch_bounds__(256) void conv1_cl(const float* __restrict__ imgs,
                                                const float* __restrict__ w1T,
                                                const float* __restrict__ bias,
                                                __hip_bfloat16* __restrict__ xc)
{
    __shared__ float simg[540];
    const int h = blockIdx.x, b = blockIdx.y, t = threadIdx.x;   // t = oc
    const float* ib = imgs + (size_t)b*3600 + h*60;
    for (int i = t; i < 540; i += 256) simg[i] = ib[i];
    float wr[81];
    #pragma unroll
    for (int j = 0; j < 81; ++j) wr[j] = w1T[j*256 + t];
    __syncthreads();
    const float bv = bias[t];
    __hip_bfloat16* xrow = xc + ((size_t)b*52 + h)*2*28*256;
    __hip_bfloat16* xb = xrow + t;
    for (int g = 0; g < 13; ++g) {
        const int w0 = g*4;
        float a0=0.f, a1=0.f, a2=0.f, a3=0.f;
        #pragma unroll
        for (int kh = 0; kh < 9; ++kh) {
            const float* rp = &simg[kh*60 + w0];
            const float4 A  = *(const float4*)rp;
            const float4 Bv = *(const float4*)(rp+4);
            const float4 C  = *(const float4*)(rp+8);
            const float r[12] = {A.x,A.y,A.z,A.w,Bv.x,Bv.y,Bv.z,Bv.w,C.x,C.y,C.z,C.w};
            const float* ww = &wr[kh*9];
            #pragma unroll
            for (int kw = 0; kw < 9; ++kw) {
                a0 = fmaf(ww[kw], r[kw+0], a0);
                a1 = fmaf(ww[kw], r[kw+1], a1);
                a2 = fmaf(ww[kw], r[kw+2], a2);
                a3 = fmaf(ww[kw], r[kw+3], a3);
            }
        }
        const float vals[4] = {a0,a1,a2,a3};
        #pragma unroll
        for (int q = 0; q < 4; ++q) {
            const int wcol = w0 + q;
            xb[((size_t)(wcol&1)*28 + (wcol>>1))*256] =
                __float2bfloat16(fmaxf(vals[q] + bv, 0.f));
        }
    }
    // zero pad cols wc=26,27 (both parities): 1024 bf16 per (b,h)
    {
        const int f = t*4;
        const int p = f >> 9, rem = f & 511;
        const int wc = 26 + (rem >> 8), ic = rem & 255;
        *(uint2*)(xrow + ((size_t)p*28 + wc)*256 + ic) = make_uint2(0u, 0u);
    }
}

// ---------------- primary caps conv: bf16 MFMA implicit GEMM, splitK=4 DETERMINISTIC
// grid (16b*6ohp, 4kpart), 256 thr = 4 waves. Block tile 256m x 96n (4 rows x 24 padded).
// A: global_load_lds (pre-swizzled source, linear LDS). B: reg prefetch + counted vmcnt.
__global__ __launch_bounds__(256, 2) void pconv_mfma(const __hip_bfloat16* __restrict__ xc,
                                                     const __hip_bfloat16* __restrict__ wA,
                                                     float* __restrict__ pc)
{
    __shared__ bf16x8 As[2048];   // [256 m][8 chunks] linear (source pre-swizzled)
    __shared__ bf16x8 Bs[768];    // [96 n][8 chunks], slot = j ^ (n&7)
    const int t = threadIdx.x;
    const int b = blockIdx.x / 6, ohp = blockIdx.x % 6;
    const int kpart = blockIdx.y;
    const int khw0  = (kpart == 0) ? 0 : (1 + 20*kpart);   // 0,21,41,61
    const int niter = (kpart == 0) ? 84 : 80;              // khw_count * 4 ic-chunks

    // A: thread t owns rows (t>>3)+32i, linear slot t&7; source chunk = slot ^ (row&7)
    const int arow = t >> 3, aj = t & 7;
    const int jsrc = aj ^ (arow & 7);
    const short* wA_s = (const short*)wA;
    const short* asrc = wA_s + (size_t)arow*20736 + khw0*256 + jsrc*8;

    // B: t<192: n = t>>1, half = t&1 -> 4 chunks of 16B
    const int bn = t >> 1, bhalf = t & 1;
    const int brr = bn / 24, bow = bn - brr*24;
    const short* xc_s = (const short*)xc;
    const size_t xbase = (size_t)b*52*2*28*256;

    bf16x8 breg[4];
    auto load_B = [&](int kt) {
        if (t < 192) {
            const int khw = khw0 + (kt >> 2), ich = kt & 3;
            const int kh = khw / 9, kw = khw - 9*kh;
            int h = 8*ohp + 2*brr + kh; if (h > 51) h = 51;   // clamp (masked rows)
            const short* src = xc_s + xbase
                + (((size_t)h*2 + (kw&1))*28 + (kw>>1) + bow)*256 + ich*64 + bhalf*32;
            #pragma unroll
            for (int c = 0; c < 4; ++c) breg[c] = *(const bf16x8*)(src + c*8);
        }
    };

    f32x4 acc[4][6];
    const f32x4 z4 = {0.f,0.f,0.f,0.f};
    #pragma unroll
    for (int mt = 0; mt < 4; ++mt)
        #pragma unroll
        for (int nt = 0; nt < 6; ++nt) acc[mt][nt] = z4;

    const int w = t >> 6, lane = t & 63, lm = lane & 15, lk = lane >> 4;
    const int swz = lm & 7;

    load_B(0);
    for (int kt = 0; kt < niter; ++kt) {
        __builtin_amdgcn_s_barrier();             // all waves done reading previous tile
        if (t < 192) {
            #pragma unroll
            for (int c = 0; c < 4; ++c)
                Bs[bn*8 + ((bhalf*4 + c) ^ (bn & 7))] = breg[c];
        }
        __builtin_amdgcn_sched_barrier(0);
        #pragma unroll
        for (int i = 0; i < 8; ++i)
            glds16(asrc + (size_t)i*32*20736 + kt*64, &As[t + 256*i]);
        __builtin_amdgcn_sched_barrier(0);
        load_B(kt + 1 < niter ? kt + 1 : kt);     // prefetch next B (stays in flight)
        if (t < 192) asm volatile("s_waitcnt vmcnt(4) lgkmcnt(0)" ::: "memory");
        else         asm volatile("s_waitcnt vmcnt(0) lgkmcnt(0)" ::: "memory");
        __builtin_amdgcn_sched_barrier(0);
        __builtin_amdgcn_s_barrier();             // tile visible to all waves
        __builtin_amdgcn_sched_barrier(0);
        #pragma unroll
        for (int ks = 0; ks < 2; ++ks) {
            const int chunk = (lk + 4*ks) ^ swz;
            bf16x8 af[4], bfr[6];
            #pragma unroll
            for (int mt = 0; mt < 4; ++mt)
                af[mt] = As[(w*64 + mt*16 + lm)*8 + chunk];
            #pragma unroll
            for (int nt = 0; nt < 6; ++nt)
                bfr[nt] = Bs[(nt*16 + lm)*8 + chunk];
            #pragma unroll
            for (int mt = 0; mt < 4; ++mt)
                #pragma unroll
                for (int nt = 0; nt < 6; ++nt)
                    acc[mt][nt] = __builtin_amdgcn_mfma_f32_16x16x32_bf16(
                        af[mt], bfr[nt], acc[mt][nt], 0, 0, 0);
        }
    }

    // epilogue: C row=(lane>>4)*4+reg, col=lane&15; plain stores into own kpart buffer
    float* pcp = pc + (size_t)kpart*NPCH;
    #pragma unroll
    for (int nt = 0; nt < 6; ++nt) {
        const int nl = nt*16 + lm;
        const int rr = nl / 24, ow = nl - rr*24;
        const int r = 4*ohp + rr;
        if (ow < 22 && r < 22) {
            const int s = r*22 + ow;
            #pragma unroll
            for (int mt = 0; mt < 4; ++mt) {
                #pragma unroll
                for (int reg = 0; reg < 4; ++reg) {
                    const int mrow = w*64 + mt*16 + lk*4 + reg;
                    pcp[((size_t)(b*256 + mrow))*484 + s] = acc[mt][nt][reg];
                }
            }
        }
    }
}

// ---------------- primary squash: fixed-order sum of 4 partials + bias -> u; U = sum_p u
__global__ __launch_bounds__(256) void psquash_kernel(const float* __restrict__ pc,
                                                      const float* __restrict__ bias,
                                                      float* __restrict__ u,
                                                      float* __restrict__ Uacc)
{
    const int b = blockIdx.y;
    const int p = blockIdx.x*256 + threadIdx.x;
    float u8[8];
    #pragma unroll
    for (int e = 0; e < 8; ++e) u8[e] = 0.f;
    if (p < PCAPS) {
        const int m = p / 484;
        const int s = p - m*484;
        float sq = 0.f;
        #pragma unroll
        for (int e = 0; e < 8; ++e) {
            const int ch = e*32 + m;
            const size_t idx = ((size_t)(b*256 + ch))*484 + s;
            const float val = pc[idx] + pc[NPCH + idx] + pc[2*NPCH + idx] + pc[3*NPCH + idx]
                            + bias[ch];
            u8[e] = val; sq += val*val;
        }
        const float scale = (sq / (1.f + sq)) / sqrtf(sq + 1e-8f);
        #pragma unroll
        for (int e = 0; e < 8; ++e) u8[e] *= scale;
        float4* up = (float4*)(u + ((size_t)b*PCAPS + p)*8);
        up[0] = make_float4(u8[0], u8[1], u8[2], u8[3]);
        up[1] = make_float4(u8[4], u8[5], u8[6], u8[7]);
    }
    #pragma unroll
    for (int off = 32; off > 0; off >>= 1) {
        #pragma unroll
        for (int e = 0; e < 8; ++e) u8[e] += __shfl_down(u8[e], off, 64);
    }
    if ((threadIdx.x & 63) == 0) {
        #pragma unroll
        for (int e = 0; e < 8; ++e) atomicAdd(&Uacc[b*8 + e], u8[e]);
    }
}

// ---------------- routing big pass
__global__ __launch_bounds__(256) void route_pass(const float* __restrict__ u,
                                                  const float* __restrict__ Wv,
                                                  float* __restrict__ Z,
                                                  float* __restrict__ tu)
{
    const int b = blockIdx.y;
    const int t = threadIdx.x;
    __shared__ float sWv[80];
    if (t < 80) sWv[t] = Wv[b*80 + t];
    __syncthreads();
    float accZ[10];
    float accT[80];
    #pragma unroll
    for (int i = 0; i < 10; ++i) accZ[i] = 0.f;
    #pragma unroll
    for (int i = 0; i < 80; ++i) accT[i] = 0.f;
    for (int p = blockIdx.x*256 + t; p < PCAPS; p += 8*256) {
        const float4* up = (const float4*)(u + ((size_t)b*PCAPS + p)*8);
        const float4 ua = up[0], ub = up[1];
        const float u8[8] = {ua.x, ua.y, ua.z, ua.w, ub.x, ub.y, ub.z, ub.w};
        #pragma unroll
        for (int c = 0; c < 10; ++c) {
            float bij = 0.f;
            #pragma unroll
            for (int e = 0; e < 8; ++e) bij = fmaf(u8[e], sWv[c*8 + e], bij);
            const float ex = __expf(bij);
            accZ[c] += ex;
            #pragma unroll
            for (int e = 0; e < 8; ++e) accT[c*8 + e] = fmaf(ex, u8[e], accT[c*8 + e]);
        }
    }
    #pragma unroll
    for (int off = 32; off > 0; off >>= 1) {
        #pragma unroll
        for (int i = 0; i < 10; ++i) accZ[i] += __shfl_down(accZ[i], off, 64);
        #pragma unroll
        for (int i = 0; i < 80; ++i) accT[i] += __shfl_down(accT[i], off, 64);
    }
    if ((t & 63) == 0) {
        #pragma unroll
        for (int c = 0; c < 10; ++c) atomicAdd(&Z[b*10 + c], accZ[c]);
        #pragma unroll
        for (int i = 0; i < 80; ++i) atomicAdd(&tu[b*80 + i], accT[i]);
    }
}

// ---------------- tiny per-(b,c) routing step; mode 2 also does head
__global__ void route_small_kernel(const float* __restrict__ W,
                                   const float* __restrict__ tu,
                                   const float* __restrict__ Z,
                                   const float* __restrict__ Uacc,
                                   float* __restrict__ WvSum,
                                   float* __restrict__ y_out,
                                   float* __restrict__ vlen_out,
                                   float* __restrict__ m,
                                   int mode)   // 0: uniform c_ij, 1: accumulate, 2: final+head
{
    __shared__ float lv[160];
    __shared__ int amax[16];
    const int t = threadIdx.x;
    int b = 0, c = 0;
    float s[16];
    float sq = 0.f, scale = 0.f;
    if (t < 160) {
        b = t / 10; c = t - b*10;
        float te[8];
        float zinv;
        if (mode == 0) {
            #pragma unroll
            for (int e = 0; e < 8; ++e) te[e] = Uacc[b*8 + e];
            zinv = 1.f / (float)PCAPS;
        } else {
            #pragma unroll
            for (int e = 0; e < 8; ++e) te[e] = tu[(b*10 + c)*8 + e];
            zinv = 1.f / Z[b*10 + c];
        }
        #pragma unroll
        for (int d = 0; d < 16; ++d) {
            float a = 0.f;
            #pragma unroll
            for (int e = 0; e < 8; ++e) a = fmaf(W[(c*16 + d)*8 + e], te[e], a);
            a *= zinv;
            s[d] = a; sq += a*a;
        }
        scale = (sq / (1.f + sq)) / sqrtf(sq + 1e-8f);
        #pragma unroll
        for (int d = 0; d < 16; ++d) s[d] *= scale;
        if (mode != 2) {
            #pragma unroll
            for (int e = 0; e < 8; ++e) {
                float a = 0.f;
                #pragma unroll
                for (int d = 0; d < 16; ++d) a = fmaf(W[(c*16 + d)*8 + e], s[d], a);
                WvSum[(b*10 + c)*8 + e] = (mode == 0) ? a : (WvSum[(b*10 + c)*8 + e] + a);
            }
        }
    }
    if (mode == 2) {
        if (t < 160) {
            const float L = sqrtf(sq) * scale;
            lv[t] = L;
            vlen_out[t] = L;
        }
        __syncthreads();
        if (t < 16) {
            int best = 0; float bv = lv[t*10];
            for (int cc = 1; cc < 10; ++cc) {
                const float val = lv[t*10 + cc];
                if (val > bv) { bv = val; best = cc; }
            }
            amax[t] = best;
        }
        __syncthreads();
        if (t < 160) {
            const bool keep = (c == amax[b]);
            y_out[t] = keep ? 1.0f : 0.0f;
            #pragma unroll
            for (int d = 0; d < 16; ++d)
                m[b*160 + c*16 + d] = keep ? s[d] : 0.0f;
        }
    }
}

// ---------------- batched decoder layer (full K, deterministic, bias+act fused)
// grid ceil(N/32), 256 thr: j = bx*32 + (t&31), kg = t>>5 over K/8 slices.
__global__ __launch_bounds__(256) void fcb_kernel(const float* __restrict__ in,
                                                  const float* __restrict__ Wm,
                                                  const float* __restrict__ bias,
                                                  float* __restrict__ outp,
                                                  int K, int N, int act)  // 0 relu, 1 sigmoid
{
    __shared__ float red[256*17];
    const int t = threadIdx.x;
    const int jl = t & 31, kg = t >> 5;
    const int j = blockIdx.x*32 + jl;
    const int jj = (j < N) ? j : N - 1;
    const int kcnt = K >> 3;
    const int ks = kg * kcnt;
    float acc[16];
    #pragma unroll
    for (int b = 0; b < 16; ++b) acc[b] = 0.f;
    for (int kk = 0; kk < kcnt; ++kk) {
        const float wv = Wm[(size_t)(ks + kk)*N + jj];
        const float* ip = in + ks + kk;
        #pragma unroll
        for (int b = 0; b < 16; ++b) acc[b] = fmaf(wv, ip[(size_t)b*K], acc[b]);
    }
    #pragma unroll
    for (int b = 0; b < 16; ++b) red[t*17 + b] = acc[b];
    __syncthreads();
    const int jo = blockIdx.x*32 + t;
    if (t < 32 && jo < N) {
        float sv = bias[jo];
        #pragma unroll
        for (int g = 0; g < 8; ++g) {
            #pragma unroll
            for (int b = 0; b < 16; ++b) {
                // accumulate per-b in registers; store after
            }
        }
        #pragma unroll
        for (int b = 0; b < 16; ++b) {
            float sb = 0.f;
            #pragma unroll
            for (int g = 0; g < 8; ++g) sb += red[(g*32 + t)*17 + b];
            const float val = sb + bias[jo];
            outp[(size_t)b*N + jo] = (act == 0) ? fmaxf(val, 0.f)
                                                : 1.f / (1.f + __expf(-val));
        }
        (void)sv;
    }
}

extern "C" void kernel_launch(void* const* d_in, const int* in_sizes, int n_in,
                              void* d_out, int out_size, void* d_ws, size_t ws_size,
                              hipStream_t stream)
{
    const float* imgs = (const float*)d_in[0];
    const float* c1w  = (const float*)d_in[1];
    const float* c1b  = (const float*)d_in[2];
    const float* pw   = (const float*)d_in[3];
    const float* pb   = (const float*)d_in[4];
    const float* Wd   = (const float*)d_in[5];
    const float* w1   = (const float*)d_in[6];
    const float* b1   = (const float*)d_in[7];
    const float* w2   = (const float*)d_in[8];
    const float* b2   = (const float*)d_in[9];
    const float* w3   = (const float*)d_in[10];
    const float* b3   = (const float*)d_in[11];

    char* wsb = (char*)d_ws;
    float* out = (float*)d_out;

    __hip_bfloat16* xcb = (__hip_bfloat16*)(wsb + OFF_XC_B);
    __hip_bfloat16* wAb = (__hip_bfloat16*)(wsb + OFF_WA_B);
    float* pc = (float*)(wsb + OFF_PC_B);
    float* u  = (float*)(wsb + OFF_U_B);
    float* sm = (float*)(wsb + OFF_SM_B);

    float* Uacc = sm + S_UACC;
    float* Z1   = sm + S_Z1;
    float* tu1  = sm + S_TU1;
    float* Z2   = sm + S_Z2;
    float* tu2  = sm + S_TU2;
    float* Wvs  = sm + S_WVS;
    float* m    = sm + S_M;
    float* h1   = sm + S_H1;
    float* h2   = sm + S_H2;
    float* w1T  = sm + S_W1T;

    // zero small accumulators only (pc partials are fully overwritten)
    hipMemsetAsync(sm, 0, 3008 * sizeof(float), stream);

    wprep_kernel<<<dim3(257), 256, 0, stream>>>(pw, c1w, wAb, w1T);
    conv1_cl<<<dim3(52, 16), 256, 0, stream>>>(imgs, w1T, c1b, xcb);
    pconv_mfma<<<dim3(96, 4), 256, 0, stream>>>(xcb, wAb, pc);
    psquash_kernel<<<dim3(61, 16), 256, 0, stream>>>(pc, pb, u, Uacc);

    // routing
    route_small_kernel<<<1, 192, 0, stream>>>(Wd, tu1, Z1, Uacc, Wvs,
                                              out, out + 160 + 57600, m, 0);
    route_pass<<<dim3(8, 16), 256, 0, stream>>>(u, Wvs, Z1, tu1);
    route_small_kernel<<<1, 192, 0, stream>>>(Wd, tu1, Z1, Uacc, Wvs,
                                              out, out + 160 + 57600, m, 1);
    route_pass<<<dim3(8, 16), 256, 0, stream>>>(u, Wvs, Z2, tu2);
    route_small_kernel<<<1, 192, 0, stream>>>(Wd, tu2, Z2, Uacc, Wvs,
                                              out, out + 160 + 57600, m, 2);

    // decoder: out layout [y_ohe 160][reconst 57600][v_length 160]
    fcb_kernel<<<dim3(16), 256, 0, stream>>>(m,  w1, b1, h1, 160, 512, 0);
    fcb_kernel<<<dim3(32), 256, 0, stream>>>(h1, w2, b2, h2, 512, 1024, 0);
    fcb_kernel<<<dim3(113), 256, 0, stream>>>(h2, w3, b3, out + 160, 1024, 3600, 1);
}